// Round 15
// baseline (249.242 us; speedup 1.0000x reference)
//
#include <hip/hip_runtime.h>
#include <hip/hip_bf16.h>

// Three-phase scheme (semantics = R9-certified HD ordering):
//   PASS 0a: X f32 -> A2 [M][2K] bf16 (Dekker planes h1|h2); resets flag ctr.
//   PASS 0b: W f32 -> BT [N][K] bf16 sign, transposed.
//   PASS 1:  bulk GEMM 256x256 tile, BK=32 real-k subtiles, PLANE-SHARED B:
//            each 48KB buffer = {A1 16K | A2 16K | B 16K}; 3 buffers (144KB),
//            2-subtile-deep prefetch, counted vmcnt(12/6/0), 2 barriers per
//            subtile (same proven skeleton as R14). B frags read once per
//            subtile and reused for both planes' MFMAs. 64B row stride ->
//            natural 2-way banking (free), linear staging, no swizzle.
//            Writes sign(D); flags |D| < TAU (=6e-3 >> 20sigma bulk err).
//   PASS 2:  wave-cooperative exact fixup (vectorized gather from X + BT);
//            HD chain: OpenBLAS Q=384 plain tail [384x5,128], ascending-k.
// Fallback (small ws / odd shapes): R12-certified fused bulk + W-column fixup.

typedef __bf16 bf16x8 __attribute__((ext_vector_type(8)));
typedef float f32x4 __attribute__((ext_vector_type(4)));

#define TAU 6e-3f

__device__ __forceinline__ float sgnf(float v) {
    return (v > 0.f) ? 1.f : ((v < 0.f) ? -1.f : 0.f);
}
__device__ __forceinline__ ushort f2bf(float x) {            // f32->bf16 RNE
    uint u = __float_as_uint(x);
    u += 0x7FFFu + ((u >> 16) & 1u);
    return (ushort)(u >> 16);
}
__device__ __forceinline__ float bf2f(ushort h) {
    return __uint_as_float(((uint)h) << 16);
}
__device__ __forceinline__ ushort sgnbf(float w) {           // sign as bf16
    return (w > 0.f) ? (ushort)0x3F80 : ((w < 0.f) ? (ushort)0xBF80 : (ushort)0);
}

// ---------------- PASS 0a: X -> Dekker bf16 planes (+ flag reset) ----------
// block = one row of X; thread j handles 8 contiguous elements. No int div.
__global__ __launch_bounds__(256)
void conv_x_planes(const float* __restrict__ X, ushort* __restrict__ A2,
                   uint* __restrict__ flags, int K)
{
    if (blockIdx.x == 0 && threadIdx.x == 0) flags[0] = 0u;

    const int m  = blockIdx.x;
    const int j8 = threadIdx.x * 8;
    if (j8 >= K) return;

    const float4 v0 = *(const float4*)&X[(size_t)m * K + j8];
    const float4 v1 = *(const float4*)&X[(size_t)m * K + j8 + 4];
    const float xs[8] = {v0.x, v0.y, v0.z, v0.w, v1.x, v1.y, v1.z, v1.w};

    ushort h1[8], h2[8];
    #pragma unroll
    for (int e = 0; e < 8; ++e) {
        h1[e] = f2bf(xs[e]);
        h2[e] = f2bf(xs[e] - bf2f(h1[e]));   // Dekker residual (exact sub)
    }
    uint4 p1, p2;
    p1.x = (uint)h1[0] | ((uint)h1[1] << 16);
    p1.y = (uint)h1[2] | ((uint)h1[3] << 16);
    p1.z = (uint)h1[4] | ((uint)h1[5] << 16);
    p1.w = (uint)h1[6] | ((uint)h1[7] << 16);
    p2.x = (uint)h2[0] | ((uint)h2[1] << 16);
    p2.y = (uint)h2[2] | ((uint)h2[3] << 16);
    p2.z = (uint)h2[4] | ((uint)h2[5] << 16);
    p2.w = (uint)h2[6] | ((uint)h2[7] << 16);

    ushort* row = A2 + (size_t)m * 2 * K;
    *(uint4*)(row + j8)     = p1;
    *(uint4*)(row + K + j8) = p2;
}

// ---------------- PASS 0b: W -> sign(W)^T bf16 ----------------
__global__ __launch_bounds__(256)
void transp_sign(const float* __restrict__ W, ushort* __restrict__ BT,
                 int K, int N)
{
    __shared__ float tile[64][65];
    const int k0 = blockIdx.y * 64;
    const int n0 = blockIdx.x * 64;
    const int tr = threadIdx.x >> 6;
    const int tc = threadIdx.x & 63;

    #pragma unroll
    for (int h = 0; h < 16; ++h) {
        const int r = h * 4 + tr;
        tile[r][tc] = W[(size_t)(k0 + r) * N + n0 + tc];
    }
    __syncthreads();

    const int nr = threadIdx.x >> 2;
    const int kc = (threadIdx.x & 3) * 16;
    ushort sb[16];
    #pragma unroll
    for (int e = 0; e < 16; ++e) sb[e] = sgnbf(tile[kc + e][nr]);

    uint4 a, b;
    a.x = (uint)sb[0]  | ((uint)sb[1]  << 16);
    a.y = (uint)sb[2]  | ((uint)sb[3]  << 16);
    a.z = (uint)sb[4]  | ((uint)sb[5]  << 16);
    a.w = (uint)sb[6]  | ((uint)sb[7]  << 16);
    b.x = (uint)sb[8]  | ((uint)sb[9]  << 16);
    b.y = (uint)sb[10] | ((uint)sb[11] << 16);
    b.z = (uint)sb[12] | ((uint)sb[13] << 16);
    b.w = (uint)sb[14] | ((uint)sb[15] << 16);

    ushort* dst = BT + (size_t)(n0 + nr) * K + k0 + kc;
    *(uint4*)dst       = a;
    *(uint4*)(dst + 8) = b;
}

// ---------------- PASS 1: 256x256, BK=32, plane-shared B, 3 buffers --------
__global__ __launch_bounds__(512, 2)
void bulk_mfma_3b(const ushort* __restrict__ A2,   // [M][2K] bf16
                  const ushort* __restrict__ BT,   // [N][K]  bf16
                  float* __restrict__ O,
                  uint* __restrict__ flags, uint cap,
                  int M, int N, int K)
{
    __shared__ __align__(16) char lds[147456];  // 3 x {A1 16K | A2 16K | B 16K}

    const int tid = threadIdx.x;
    const int l   = tid & 63;
    const int wid = tid >> 6;          // 0..7
    const int wm  = wid >> 2;          // 0..1
    const int wn  = wid & 3;           // 0..3
    const int lr  = l & 15;
    const int lk  = l >> 4;

    // bijective XCD swizzle (nwg % 8 == 0)
    const int nwg = gridDim.x;
    int wg = blockIdx.x;
    wg = (wg & 7) * (nwg >> 3) + (wg >> 3);
    const int nbx = N >> 8;
    const int m0 = (wg / nbx) << 8;
    const int n0 = (wg % nbx) << 8;

    const int NS = K >> 5;             // 32k subtiles (64)
    const size_t rowA = (size_t)(2 * K) * 2;   // bytes per A2 row
    const size_t rowB = (size_t)K * 2;
    const char* A2b = (const char*)A2;
    const char* BTb = (const char*)BT;

    f32x4 acc[8][4];
    #pragma unroll
    for (int i = 0; i < 8; ++i)
        #pragma unroll
        for (int j = 0; j < 4; ++j)
            acc[i][j] = (f32x4){0.f, 0.f, 0.f, 0.f};

    // stage subtile s into buffer buf: 6 gload_lds/thread, LINEAR layout.
    // Each 16KB plane-tile = 16 chunks of 1KB (16 rows x 64B); wave wid
    // stages chunks {2wid, 2wid+1}. Lane l -> row c*16 + (l>>2),
    // byte (l&3)*16 (matches HW dst = base + lane*16).
    auto STAGE = [&](int buf, int s) {
        char* base = lds + buf * 49152;
        const size_t kOff = (size_t)s << 6;        // s*32 elems * 2B
        #pragma unroll
        for (int h = 0; h < 2; ++h) {
            const int c   = wid * 2 + h;           // chunk 0..15
            const int row = c * 16 + (l >> 2);
            const int byt = (l & 3) << 4;
            // A plane 1
            const char* sA1 = A2b + (size_t)(m0 + row) * rowA + kOff + byt;
            __builtin_amdgcn_global_load_lds(
                (const __attribute__((address_space(1))) void*)sA1,
                (__attribute__((address_space(3))) void*)(base + c * 1024),
                16, 0, 0);
            // A plane 2 (column offset +K elements = +2K bytes)
            const char* sA2 = sA1 + (size_t)K * 2;
            __builtin_amdgcn_global_load_lds(
                (const __attribute__((address_space(1))) void*)sA2,
                (__attribute__((address_space(3))) void*)(base + 16384 + c * 1024),
                16, 0, 0);
            // B
            const char* sB = BTb + (size_t)(n0 + row) * rowB + kOff + byt;
            __builtin_amdgcn_global_load_lds(
                (const __attribute__((address_space(1))) void*)sB,
                (__attribute__((address_space(3))) void*)(base + 32768 + c * 1024),
                16, 0, 0);
        }
    };

    // compute subtile from buffer: B frags once, reused for both A planes.
    auto COMPUTE = [&](int buf) {
        const char* base = lds + buf * 49152;
        const char* pB   = base + 32768;
        bf16x8 bg[4];
        #pragma unroll
        for (int j = 0; j < 4; ++j) {
            const int row = wn * 64 + j * 16 + lr;
            bg[j] = *(const bf16x8*)(pB + row * 64 + lk * 16);
        }
        #pragma unroll
        for (int pl = 0; pl < 2; ++pl) {
            const char* pA = base + pl * 16384;
            bf16x8 af[8];
            #pragma unroll
            for (int i = 0; i < 8; ++i) {
                const int row = wm * 128 + i * 16 + lr;
                af[i] = *(const bf16x8*)(pA + row * 64 + lk * 16);
            }
            #pragma unroll
            for (int i = 0; i < 8; ++i)
                #pragma unroll
                for (int j = 0; j < 4; ++j)
                    acc[i][j] = __builtin_amdgcn_mfma_f32_16x16x32_bf16(
                        af[i], bg[j], acc[i][j], 0, 0, 0);
        }
    };

    // prologue: 3 subtiles in flight (18 loads/thread)
    STAGE(0, 0);
    STAGE(1, 1);
    STAGE(2, 2);

    for (int s = 0; s < NS; ++s) {
        // drain subtile s's 6 loads; keep later subtiles in flight
        const int nw = ((NS < s + 3) ? NS : (s + 3)) - (s + 1);
        if (nw == 2)      asm volatile("s_waitcnt vmcnt(12)" ::: "memory");
        else if (nw == 1) asm volatile("s_waitcnt vmcnt(6)"  ::: "memory");
        else              asm volatile("s_waitcnt vmcnt(0)"  ::: "memory");
        __builtin_amdgcn_s_barrier();
        __builtin_amdgcn_sched_barrier(0);
        COMPUTE(s % 3);
        __builtin_amdgcn_s_barrier();
        __builtin_amdgcn_sched_barrier(0);
        if (s + 3 < NS) STAGE(s % 3, s + 3);   // refill just-freed buffer
    }

    // epilogue: sign + borderline flagging (C/D: col=lane&15, row=lk*4+q)
    #pragma unroll
    for (int i = 0; i < 8; ++i) {
        #pragma unroll
        for (int j = 0; j < 4; ++j) {
            #pragma unroll
            for (int q = 0; q < 4; ++q) {
                const int m = m0 + wm * 128 + i * 16 + lk * 4 + q;
                const int n = n0 + wn * 64 + j * 16 + lr;
                const float d = acc[i][j][q];
                const size_t oi = (size_t)m * N + n;
                O[oi] = sgnf(d);
                if (fabsf(d) < TAU) {
                    const uint pos = atomicAdd(flags, 1u);
                    if (pos < cap) flags[1 + pos] = (uint)oi;
                }
            }
        }
    }
}

// ---------------- FALLBACK bulk (R12-certified, fused conversion) ----------
__global__ __launch_bounds__(256, 2)
void bulk_mfma_fb(const float* __restrict__ X, const float* __restrict__ W,
                  float* __restrict__ O, uint* __restrict__ flags,
                  uint cap, int M, int N, int K)
{
    __shared__ __align__(16) char sA[128 * 128];
    __shared__ __align__(16) char sB[128 * 128];

    const int tid = threadIdx.x;
    const int l   = tid & 63;
    const int w   = tid >> 6;
    const int wr  = w >> 1, wc = w & 1;
    const int lr  = l & 15;
    const int lk  = l >> 4;

    const int m0 = blockIdx.y * 128;
    const int n0 = blockIdx.x * 128;

    f32x4 acc[4][4];
    #pragma unroll
    for (int i = 0; i < 4; ++i)
        #pragma unroll
        for (int j = 0; j < 4; ++j)
            acc[i][j] = (f32x4){0.f, 0.f, 0.f, 0.f};

    const int NT = K / 64;

    for (int kt = 0; kt < 2 * NT; ++kt) {
        const int plane = (kt >= NT);
        const int kr0 = (plane ? (kt - NT) : kt) * 64;

        #pragma unroll
        for (int h = 0; h < 4; ++h) {
            const int idx = tid + 256 * h;
            const int r   = idx >> 3;
            const int c8  = (idx & 7) * 8;
            const float* xp = &X[(size_t)(m0 + r) * K + kr0 + c8];
            const float4 v0 = *(const float4*)xp;
            const float4 v1 = *(const float4*)(xp + 4);
            const float xs[8] = {v0.x, v0.y, v0.z, v0.w, v1.x, v1.y, v1.z, v1.w};
            ushort hb[8];
            if (!plane) {
                #pragma unroll
                for (int e = 0; e < 8; ++e) hb[e] = f2bf(xs[e]);
            } else {
                #pragma unroll
                for (int e = 0; e < 8; ++e) {
                    const ushort h1 = f2bf(xs[e]);
                    hb[e] = f2bf(xs[e] - bf2f(h1));
                }
            }
            uint4 pk;
            pk.x = (uint)hb[0] | ((uint)hb[1] << 16);
            pk.y = (uint)hb[2] | ((uint)hb[3] << 16);
            pk.z = (uint)hb[4] | ((uint)hb[5] << 16);
            pk.w = (uint)hb[6] | ((uint)hb[7] << 16);
            *(uint4*)(sA + r * 128 + ((c8 * 2) ^ ((r & 7) << 4))) = pk;
        }
        {
            const int ko = (tid >> 5) * 8;
            const int n4 = (tid & 31) * 4;
            float4 rv[8];
            #pragma unroll
            for (int j = 0; j < 8; ++j)
                rv[j] = *(const float4*)&W[(size_t)(kr0 + ko + j) * N + n0 + n4];
            #pragma unroll
            for (int c = 0; c < 4; ++c) {
                ushort sb[8];
                #pragma unroll
                for (int j = 0; j < 8; ++j)
                    sb[j] = sgnbf(((const float*)&rv[j])[c]);
                uint4 pk;
                pk.x = (uint)sb[0] | ((uint)sb[1] << 16);
                pk.y = (uint)sb[2] | ((uint)sb[3] << 16);
                pk.z = (uint)sb[4] | ((uint)sb[5] << 16);
                pk.w = (uint)sb[6] | ((uint)sb[7] << 16);
                const int row = n4 + c;
                *(uint4*)(sB + row * 128 + ((ko * 2) ^ ((row & 7) << 4))) = pk;
            }
        }
        __syncthreads();

        #pragma unroll
        for (int kk = 0; kk < 2; ++kk) {
            const int kb = kk * 64 + lk * 16;
            bf16x8 af[4], bg[4];
            #pragma unroll
            for (int i = 0; i < 4; ++i) {
                const int row = wr * 64 + i * 16 + lr;
                af[i] = *(const bf16x8*)(sA + row * 128 + (kb ^ ((row & 7) << 4)));
            }
            #pragma unroll
            for (int j = 0; j < 4; ++j) {
                const int row = wc * 64 + j * 16 + lr;
                bg[j] = *(const bf16x8*)(sB + row * 128 + (kb ^ ((row & 7) << 4)));
            }
            #pragma unroll
            for (int i = 0; i < 4; ++i)
                #pragma unroll
                for (int j = 0; j < 4; ++j)
                    acc[i][j] = __builtin_amdgcn_mfma_f32_16x16x32_bf16(
                        af[i], bg[j], acc[i][j], 0, 0, 0);
        }
        __syncthreads();
    }

    #pragma unroll
    for (int i = 0; i < 4; ++i) {
        #pragma unroll
        for (int j = 0; j < 4; ++j) {
            #pragma unroll
            for (int q = 0; q < 4; ++q) {
                const int m = m0 + wr * 64 + i * 16 + lk * 4 + q;
                const int n = n0 + wc * 64 + j * 16 + lr;
                const float d = acc[i][j][q];
                const size_t oi = (size_t)m * N + n;
                O[oi] = sgnf(d);
                if (fabsf(d) < TAU) {
                    const uint pos = atomicAdd(flags, 1u);
                    if (pos < cap) flags[1 + pos] = (uint)oi;
                }
            }
        }
    }
}

// ---------------- PASS 2: fixup reading BT (vectorized gather) -------------
__global__ __launch_bounds__(64)
void fixup_exact_bt(const float* __restrict__ X, const ushort* __restrict__ BT,
                    float* __restrict__ O, const uint* __restrict__ flags,
                    uint cap, int K, int N)
{
    __shared__ float p[2048];

    uint count = flags[0];
    if (count > cap) count = cap;

    for (uint t = blockIdx.x; t < count; t += gridDim.x) {
        const uint idx = flags[1 + t];
        const int n = (int)(idx % (uint)N);
        const float* xrow = X + (size_t)(idx / (uint)N) * K;
        const ushort* brow = BT + (size_t)n * K;

        for (int k4 = threadIdx.x * 4; k4 < K; k4 += 256) {
            const float4 xv = *(const float4*)&xrow[k4];
            const ushort4 bv = *(const ushort4*)&brow[k4];
            float4 pr;
            pr.x = xv.x * bf2f(bv.x);
            pr.y = xv.y * bf2f(bv.y);
            pr.z = xv.z * bf2f(bv.z);
            pr.w = xv.w * bf2f(bv.w);
            *(float4*)&p[k4] = pr;       // exact +-x products
        }
        __syncthreads();
        if (threadIdx.x == 0) {
            float sum = 0.f;
            int ls = 0;
            while (ls < K) {                 // HD panels [384x5,128]
                const int ke = (ls + 384 < K) ? (ls + 384) : K;
                float part = 0.f;
                for (int k = ls; k < ke; ++k) part += p[k];
                sum += part;
                ls = ke;
            }
            O[idx] = sgnf(sum);
        }
        __syncthreads();
    }
}

// ---------------- fallback fixup (reads W columns) ----------------
__global__ __launch_bounds__(64)
void fixup_exact_wave(const float* __restrict__ X, const float* __restrict__ W,
                      float* __restrict__ O, const uint* __restrict__ flags,
                      uint cap, int K, int N)
{
    __shared__ float p[2048];

    uint count = flags[0];
    if (count > cap) count = cap;

    for (uint t = blockIdx.x; t < count; t += gridDim.x) {
        const uint idx = flags[1 + t];
        const int n = (int)(idx % (uint)N);
        const float* xrow = X + (size_t)(idx / (uint)N) * K;
        const float* wcol = W + n;

        if (K <= 2048) {
            for (int k = threadIdx.x; k < K; k += 64)
                p[k] = xrow[k] * sgnf(wcol[(size_t)k * N]);
            __syncthreads();
            if (threadIdx.x == 0) {
                float sum = 0.f;
                int ls = 0;
                while (ls < K) {
                    const int ke = (ls + 384 < K) ? (ls + 384) : K;
                    float part = 0.f;
                    for (int k = ls; k < ke; ++k) part += p[k];
                    sum += part;
                    ls = ke;
                }
                O[idx] = sgnf(sum);
            }
            __syncthreads();
        } else if (threadIdx.x == 0) {
            float sum = 0.f;
            int ls = 0;
            while (ls < K) {
                const int ke = (ls + 384 < K) ? (ls + 384) : K;
                float part = 0.f;
                for (int k = ls; k < ke; ++k)
                    part = fmaf(xrow[k], sgnf(wcol[(size_t)k * N]), part);
                sum += part;
                ls = ke;
            }
            O[idx] = sgnf(sum);
        }
    }
}

extern "C" void kernel_launch(void* const* d_in, const int* in_sizes, int n_in,
                              void* d_out, int out_size, void* d_ws, size_t ws_size,
                              hipStream_t stream) {
    // order-robust input binding (x = larger buffer)
    const float* X;
    const float* W;
    long long wsize;
    if ((long long)in_sizes[0] >= (long long)in_sizes[1]) {
        X = (const float*)d_in[0];
        W = (const float*)d_in[1]; wsize = in_sizes[1];
    } else {
        X = (const float*)d_in[1];
        W = (const float*)d_in[0]; wsize = in_sizes[0];
    }
    float* O = (float*)d_out;

    int K = 1;
    while ((long long)K * K < wsize) ++K;        // K = 2048
    const int N = K;
    const int M = (int)((long long)out_size / N);

    const size_t A2_BYTES = (size_t)M * 2 * K * 2;   // 64 MB
    const size_t BT_BYTES = (size_t)N * K * 2;       // 8 MB
    const size_t FLAG_OFF = A2_BYTES + BT_BYTES;
    const bool big_ws = (ws_size >= FLAG_OFF + (1u << 16)) &&
                        (M % 256 == 0) && (N % 256 == 0) &&
                        (K % 32 == 0) && (K <= 2048) && ((K & 7) == 0) &&
                        (K <= 2048) && (K >= 256);

    if (big_ws) {
        ushort* A2 = (ushort*)d_ws;
        ushort* BT = (ushort*)((char*)d_ws + A2_BYTES);
        uint* flags = (uint*)((char*)d_ws + FLAG_OFF);
        unsigned long long c = (unsigned long long)((ws_size - FLAG_OFF) / 4) - 1ull;
        const uint cap = (uint)((c > 0x00FFFFFFull) ? 0x00FFFFFFull : c);

        conv_x_planes<<<M, 256, 0, stream>>>(X, A2, flags, K);
        dim3 tg(N / 64, K / 64);
        transp_sign<<<tg, 256, 0, stream>>>(W, BT, K, N);
        const int nwg = (N / 256) * (M / 256);       // 256, % 8 == 0
        bulk_mfma_3b<<<nwg, 512, 0, stream>>>(A2, BT, O, flags, cap, M, N, K);
        fixup_exact_bt<<<2048, 64, 0, stream>>>(X, BT, O, flags, cap, K, N);
    } else {
        uint* flags = (uint*)d_ws;
        uint cap = 0;
        if (ws_size >= 8) {
            unsigned long long c = (unsigned long long)(ws_size / 4) - 1ull;
            cap = (uint)((c > 0x00FFFFFFull) ? 0x00FFFFFFull : c);
        }
        hipMemsetAsync(d_ws, 0, 4, stream);
        dim3 grid(N / 128, M / 128);
        bulk_mfma_fb<<<grid, 256, 0, stream>>>(X, W, O, flags, cap, M, N, K);
        fixup_exact_wave<<<2048, 64, 0, stream>>>(X, W, O, flags, cap, K, N);
    }
}

// Round 16
// 181.150 us; speedup vs baseline: 1.3759x; 1.3759x over previous
//
#include <hip/hip_runtime.h>
#include <hip/hip_bf16.h>

// Three-phase scheme (semantics = R9-certified HD ordering):
//   PASS 0 (fused): X -> A2 [M][2K] bf16 Dekker planes; W -> BT [N][K] bf16
//            sign transposed; flag counter reset.
//   PASS 1:  bulk GEMM 256x256, BK=32, plane-shared B, 3 buffers, counted
//            vmcnt(12/6/0). LDS rows are 128B with XOR swizzle (R14-proven):
//            A row = {h1 64B | h2 64B}, B row = {n=2p | n=2p+1}; byte ^=
//            ((row&7)<<4) on BOTH staging-source and read (involution).
//            Writes sign(D); flags |D| < TAU (=6e-3 >> 20sigma bulk err).
//   PASS 2:  wave-cooperative exact fixup: 64-lane gather of exact +-x
//            products, then HD panels [384x5,128] computed on 6 lanes
//            (each panel internally ascending-k sequential) and folded
//            left-to-right — bit-identical to the certified chain.
// Fallback (small ws / odd shapes): R12-certified fused bulk + W-col fixup.

typedef __bf16 bf16x8 __attribute__((ext_vector_type(8)));
typedef float f32x4 __attribute__((ext_vector_type(4)));

#define TAU 6e-3f

__device__ __forceinline__ float sgnf(float v) {
    return (v > 0.f) ? 1.f : ((v < 0.f) ? -1.f : 0.f);
}
__device__ __forceinline__ ushort f2bf(float x) {            // f32->bf16 RNE
    uint u = __float_as_uint(x);
    u += 0x7FFFu + ((u >> 16) & 1u);
    return (ushort)(u >> 16);
}
__device__ __forceinline__ float bf2f(ushort h) {
    return __uint_as_float(((uint)h) << 16);
}
__device__ __forceinline__ ushort sgnbf(float w) {           // sign as bf16
    return (w > 0.f) ? (ushort)0x3F80 : ((w < 0.f) ? (ushort)0xBF80 : (ushort)0);
}

// ---------------- PASS 0: fused pre-pass (conv rows + transpose tiles) -----
__global__ __launch_bounds__(256)
void pre_pass(const float* __restrict__ X, const float* __restrict__ W,
              ushort* __restrict__ A2, ushort* __restrict__ BT,
              uint* __restrict__ flags, int M, int K, int N)
{
    __shared__ float tile[64][65];
    const int b = blockIdx.x;

    if (b == 0 && threadIdx.x == 0) flags[0] = 0u;

    if (b < M) {
        // ---- conv: one X row -> Dekker planes ----
        const int m  = b;
        const int j8 = threadIdx.x * 8;
        if (j8 >= K) return;

        const float4 v0 = *(const float4*)&X[(size_t)m * K + j8];
        const float4 v1 = *(const float4*)&X[(size_t)m * K + j8 + 4];
        const float xs[8] = {v0.x, v0.y, v0.z, v0.w, v1.x, v1.y, v1.z, v1.w};

        ushort h1[8], h2[8];
        #pragma unroll
        for (int e = 0; e < 8; ++e) {
            h1[e] = f2bf(xs[e]);
            h2[e] = f2bf(xs[e] - bf2f(h1[e]));   // exact residual
        }
        uint4 p1, p2;
        p1.x = (uint)h1[0] | ((uint)h1[1] << 16);
        p1.y = (uint)h1[2] | ((uint)h1[3] << 16);
        p1.z = (uint)h1[4] | ((uint)h1[5] << 16);
        p1.w = (uint)h1[6] | ((uint)h1[7] << 16);
        p2.x = (uint)h2[0] | ((uint)h2[1] << 16);
        p2.y = (uint)h2[2] | ((uint)h2[3] << 16);
        p2.z = (uint)h2[4] | ((uint)h2[5] << 16);
        p2.w = (uint)h2[6] | ((uint)h2[7] << 16);

        ushort* row = A2 + (size_t)m * 2 * K;
        *(uint4*)(row + j8)     = p1;
        *(uint4*)(row + K + j8) = p2;
    } else {
        // ---- transpose: one 64x64 W tile -> BT signs ----
        const int tb  = b - M;
        const int nbx = N >> 6;
        const int k0  = (tb / nbx) * 64;
        const int n0  = (tb % nbx) * 64;
        const int tr  = threadIdx.x >> 6;
        const int tc  = threadIdx.x & 63;

        #pragma unroll
        for (int h = 0; h < 16; ++h) {
            const int r = h * 4 + tr;
            tile[r][tc] = W[(size_t)(k0 + r) * N + n0 + tc];
        }
        __syncthreads();

        const int nr = threadIdx.x >> 2;
        const int kc = (threadIdx.x & 3) * 16;
        ushort sb[16];
        #pragma unroll
        for (int e = 0; e < 16; ++e) sb[e] = sgnbf(tile[kc + e][nr]);

        uint4 a2, b2;
        a2.x = (uint)sb[0]  | ((uint)sb[1]  << 16);
        a2.y = (uint)sb[2]  | ((uint)sb[3]  << 16);
        a2.z = (uint)sb[4]  | ((uint)sb[5]  << 16);
        a2.w = (uint)sb[6]  | ((uint)sb[7]  << 16);
        b2.x = (uint)sb[8]  | ((uint)sb[9]  << 16);
        b2.y = (uint)sb[10] | ((uint)sb[11] << 16);
        b2.z = (uint)sb[12] | ((uint)sb[13] << 16);
        b2.w = (uint)sb[14] | ((uint)sb[15] << 16);

        ushort* dst = BT + (size_t)(n0 + nr) * K + k0 + kc;
        *(uint4*)dst       = a2;
        *(uint4*)(dst + 8) = b2;
    }
}

// ---------------- PASS 1: 256x256, BK=32, paired 128B rows + XOR swizzle ---
__global__ __launch_bounds__(512, 2)
void bulk_mfma_3c(const ushort* __restrict__ A2,   // [M][2K] bf16
                  const ushort* __restrict__ BT,   // [N][K]  bf16
                  float* __restrict__ O,
                  uint* __restrict__ flags, uint cap,
                  int M, int N, int K)
{
    __shared__ __align__(16) char lds[147456];  // 3 x {A 32KB | B 16KB}

    const int tid = threadIdx.x;
    const int l   = tid & 63;
    const int wid = tid >> 6;          // 0..7
    const int wm  = wid >> 2;          // 0..1
    const int wn  = wid & 3;           // 0..3
    const int lr  = l & 15;
    const int lk  = l >> 4;

    // bijective XCD swizzle (nwg % 8 == 0)
    const int nwg = gridDim.x;
    int wg = blockIdx.x;
    wg = (wg & 7) * (nwg >> 3) + (wg >> 3);
    const int nbx = N >> 8;
    const int m0 = (wg / nbx) << 8;
    const int n0 = (wg % nbx) << 8;

    const int NS = K >> 5;             // 32-k subtiles (64)
    const size_t rowA = (size_t)(2 * K) * 2;   // bytes per A2 row
    const size_t rowB = (size_t)K * 2;
    const char* A2b = (const char*)A2;
    const char* BTb = (const char*)BT;

    f32x4 acc[8][4];
    #pragma unroll
    for (int i = 0; i < 8; ++i)
        #pragma unroll
        for (int j = 0; j < 4; ++j)
            acc[i][j] = (f32x4){0.f, 0.f, 0.f, 0.f};

    // Stage subtile s into buffer buf: 6 gload_lds/thread.
    // LDS A: [256 rows][128B = {h1|h2}], swizzled; chunk = 8 rows = 1KB.
    // LDS B: [128 pair-rows][128B = {n=2p|n=2p+1}], swizzled.
    // Lane-pure inverse swizzle: dst byte (l&7)*16, row-in-chunk l>>3 ->
    //   sub = ((l&7)^(l>>3))<<4; bit6 of sub selects plane (A) / odd row (B).
    auto STAGE = [&](int buf, int s) {
        char* base = lds + buf * 49152;
        const size_t kOff = (size_t)s << 6;        // s*32 elems * 2B
        const int sub  = (((l & 7) ^ (l >> 3)) << 4);
        const int lrow = l >> 3;
        #pragma unroll
        for (int h = 0; h < 4; ++h) {              // A: 4 chunks/wave
            const int c   = wid * 4 + h;           // 0..31
            const int row = c * 8 + lrow;          // 0..255
            const size_t srcOff = kOff + (size_t)(sub & 63)
                                + ((sub & 64) ? (size_t)(2 * K) : 0);
            const char* srcA = A2b + (size_t)(m0 + row) * rowA + srcOff;
            __builtin_amdgcn_global_load_lds(
                (const __attribute__((address_space(1))) void*)srcA,
                (__attribute__((address_space(3))) void*)(base + c * 1024),
                16, 0, 0);
        }
        #pragma unroll
        for (int h = 0; h < 2; ++h) {              // B: 2 chunks/wave
            const int c = wid * 2 + h;             // 0..15
            const int p = c * 8 + lrow;            // 0..127
            const int nrow = 2 * p + ((sub >> 6) & 1);
            const char* srcB = BTb + (size_t)(n0 + nrow) * rowB
                             + kOff + (size_t)(sub & 63);
            __builtin_amdgcn_global_load_lds(
                (const __attribute__((address_space(1))) void*)srcB,
                (__attribute__((address_space(3))) void*)(base + 32768 + c * 1024),
                16, 0, 0);
        }
    };

    // Compute subtile: B frags once, reused for both A planes.
    auto COMPUTE = [&](int buf) {
        const char* sA = lds + buf * 49152;
        const char* sB = sA + 32768;
        bf16x8 bg[4];
        #pragma unroll
        for (int j = 0; j < 4; ++j) {
            const int r = wn * 64 + j * 16 + lr;
            const int p = r >> 1;
            const int byt = ((r & 1) * 64 + lk * 16) ^ ((p & 7) << 4);
            bg[j] = *(const bf16x8*)(sB + p * 128 + byt);
        }
        #pragma unroll
        for (int pl = 0; pl < 2; ++pl) {
            bf16x8 af[8];
            #pragma unroll
            for (int i = 0; i < 8; ++i) {
                const int row = wm * 128 + i * 16 + lr;
                const int byt = (pl * 64 + lk * 16) ^ ((row & 7) << 4);
                af[i] = *(const bf16x8*)(sA + row * 128 + byt);
            }
            #pragma unroll
            for (int i = 0; i < 8; ++i)
                #pragma unroll
                for (int j = 0; j < 4; ++j)
                    acc[i][j] = __builtin_amdgcn_mfma_f32_16x16x32_bf16(
                        af[i], bg[j], acc[i][j], 0, 0, 0);
        }
    };

    // prologue: 3 subtiles in flight (18 loads/thread)
    STAGE(0, 0);
    STAGE(1, 1);
    STAGE(2, 2);

    for (int s = 0; s < NS; ++s) {
        const int nw = ((NS < s + 3) ? NS : (s + 3)) - (s + 1);
        if (nw == 2)      asm volatile("s_waitcnt vmcnt(12)" ::: "memory");
        else if (nw == 1) asm volatile("s_waitcnt vmcnt(6)"  ::: "memory");
        else              asm volatile("s_waitcnt vmcnt(0)"  ::: "memory");
        __builtin_amdgcn_s_barrier();
        __builtin_amdgcn_sched_barrier(0);
        COMPUTE(s % 3);
        __builtin_amdgcn_s_barrier();
        __builtin_amdgcn_sched_barrier(0);
        if (s + 3 < NS) STAGE(s % 3, s + 3);   // refill just-freed buffer
    }

    // epilogue: sign + borderline flagging (C/D: col=lane&15, row=lk*4+q)
    #pragma unroll
    for (int i = 0; i < 8; ++i) {
        #pragma unroll
        for (int j = 0; j < 4; ++j) {
            #pragma unroll
            for (int q = 0; q < 4; ++q) {
                const int m = m0 + wm * 128 + i * 16 + lk * 4 + q;
                const int n = n0 + wn * 64 + j * 16 + lr;
                const float d = acc[i][j][q];
                const size_t oi = (size_t)m * N + n;
                O[oi] = sgnf(d);
                if (fabsf(d) < TAU) {
                    const uint pos = atomicAdd(flags, 1u);
                    if (pos < cap) flags[1 + pos] = (uint)oi;
                }
            }
        }
    }
}

// ---------------- FALLBACK bulk (R12-certified, fused conversion) ----------
__global__ __launch_bounds__(256, 2)
void bulk_mfma_fb(const float* __restrict__ X, const float* __restrict__ W,
                  float* __restrict__ O, uint* __restrict__ flags,
                  uint cap, int M, int N, int K)
{
    __shared__ __align__(16) char sA[128 * 128];
    __shared__ __align__(16) char sB[128 * 128];

    const int tid = threadIdx.x;
    const int l   = tid & 63;
    const int w   = tid >> 6;
    const int wr  = w >> 1, wc = w & 1;
    const int lr  = l & 15;
    const int lk  = l >> 4;

    const int m0 = blockIdx.y * 128;
    const int n0 = blockIdx.x * 128;

    f32x4 acc[4][4];
    #pragma unroll
    for (int i = 0; i < 4; ++i)
        #pragma unroll
        for (int j = 0; j < 4; ++j)
            acc[i][j] = (f32x4){0.f, 0.f, 0.f, 0.f};

    const int NT = K / 64;

    for (int kt = 0; kt < 2 * NT; ++kt) {
        const int plane = (kt >= NT);
        const int kr0 = (plane ? (kt - NT) : kt) * 64;

        #pragma unroll
        for (int h = 0; h < 4; ++h) {
            const int idx = tid + 256 * h;
            const int r   = idx >> 3;
            const int c8  = (idx & 7) * 8;
            const float* xp = &X[(size_t)(m0 + r) * K + kr0 + c8];
            const float4 v0 = *(const float4*)xp;
            const float4 v1 = *(const float4*)(xp + 4);
            const float xs[8] = {v0.x, v0.y, v0.z, v0.w, v1.x, v1.y, v1.z, v1.w};
            ushort hb[8];
            if (!plane) {
                #pragma unroll
                for (int e = 0; e < 8; ++e) hb[e] = f2bf(xs[e]);
            } else {
                #pragma unroll
                for (int e = 0; e < 8; ++e) {
                    const ushort h1 = f2bf(xs[e]);
                    hb[e] = f2bf(xs[e] - bf2f(h1));
                }
            }
            uint4 pk;
            pk.x = (uint)hb[0] | ((uint)hb[1] << 16);
            pk.y = (uint)hb[2] | ((uint)hb[3] << 16);
            pk.z = (uint)hb[4] | ((uint)hb[5] << 16);
            pk.w = (uint)hb[6] | ((uint)hb[7] << 16);
            *(uint4*)(sA + r * 128 + ((c8 * 2) ^ ((r & 7) << 4))) = pk;
        }
        {
            const int ko = (tid >> 5) * 8;
            const int n4 = (tid & 31) * 4;
            float4 rv[8];
            #pragma unroll
            for (int j = 0; j < 8; ++j)
                rv[j] = *(const float4*)&W[(size_t)(kr0 + ko + j) * N + n0 + n4];
            #pragma unroll
            for (int c = 0; c < 4; ++c) {
                ushort sb[8];
                #pragma unroll
                for (int j = 0; j < 8; ++j)
                    sb[j] = sgnbf(((const float*)&rv[j])[c]);
                uint4 pk;
                pk.x = (uint)sb[0] | ((uint)sb[1] << 16);
                pk.y = (uint)sb[2] | ((uint)sb[3] << 16);
                pk.z = (uint)sb[4] | ((uint)sb[5] << 16);
                pk.w = (uint)sb[6] | ((uint)sb[7] << 16);
                const int row = n4 + c;
                *(uint4*)(sB + row * 128 + ((ko * 2) ^ ((row & 7) << 4))) = pk;
            }
        }
        __syncthreads();

        #pragma unroll
        for (int kk = 0; kk < 2; ++kk) {
            const int kb = kk * 64 + lk * 16;
            bf16x8 af[4], bg[4];
            #pragma unroll
            for (int i = 0; i < 4; ++i) {
                const int row = wr * 64 + i * 16 + lr;
                af[i] = *(const bf16x8*)(sA + row * 128 + (kb ^ ((row & 7) << 4)));
            }
            #pragma unroll
            for (int j = 0; j < 4; ++j) {
                const int row = wc * 64 + j * 16 + lr;
                bg[j] = *(const bf16x8*)(sB + row * 128 + (kb ^ ((row & 7) << 4)));
            }
            #pragma unroll
            for (int i = 0; i < 4; ++i)
                #pragma unroll
                for (int j = 0; j < 4; ++j)
                    acc[i][j] = __builtin_amdgcn_mfma_f32_16x16x32_bf16(
                        af[i], bg[j], acc[i][j], 0, 0, 0);
        }
        __syncthreads();
    }

    #pragma unroll
    for (int i = 0; i < 4; ++i) {
        #pragma unroll
        for (int j = 0; j < 4; ++j) {
            #pragma unroll
            for (int q = 0; q < 4; ++q) {
                const int m = m0 + wr * 64 + i * 16 + lk * 4 + q;
                const int n = n0 + wc * 64 + j * 16 + lr;
                const float d = acc[i][j][q];
                const size_t oi = (size_t)m * N + n;
                O[oi] = sgnf(d);
                if (fabsf(d) < TAU) {
                    const uint pos = atomicAdd(flags, 1u);
                    if (pos < cap) flags[1 + pos] = (uint)oi;
                }
            }
        }
    }
}

// ---------------- PASS 2: fixup, BT gather + 6-lane panel-parallel chain ---
__global__ __launch_bounds__(64)
void fixup_exact_bt(const float* __restrict__ X, const ushort* __restrict__ BT,
                    float* __restrict__ O, const uint* __restrict__ flags,
                    uint cap, int K, int N)
{
    __shared__ float p[2048];

    uint count = flags[0];
    if (count > cap) count = cap;

    for (uint t = blockIdx.x; t < count; t += gridDim.x) {
        const uint idx = flags[1 + t];
        const int n = (int)(idx % (uint)N);
        const float* xrow = X + (size_t)(idx / (uint)N) * K;
        const ushort* brow = BT + (size_t)n * K;

        for (int k4 = threadIdx.x * 4; k4 < K; k4 += 256) {
            const float4 xv = *(const float4*)&xrow[k4];
            const ushort4 bv = *(const ushort4*)&brow[k4];
            float4 pr;
            pr.x = xv.x * bf2f(bv.x);
            pr.y = xv.y * bf2f(bv.y);
            pr.z = xv.z * bf2f(bv.z);
            pr.w = xv.w * bf2f(bv.w);
            *(float4*)&p[k4] = pr;       // exact +-x products
        }
        __syncthreads();

        // HD panels [384x5,128]: panel t on lane t (each internally
        // sequential ascending-k), folded left-to-right (exact order).
        float partial = 0.f;
        const int ls = (int)threadIdx.x * 384;
        if (ls < K) {
            const int ke = (ls + 384 < K) ? (ls + 384) : K;
            for (int k = ls; k < ke; ++k) partial += p[k];
        }
        float sum = 0.f;
        #pragma unroll
        for (int q = 0; q < 6; ++q) sum += __shfl(partial, q);
        if (threadIdx.x == 0) O[idx] = sgnf(sum);
        __syncthreads();
    }
}

// ---------------- fallback fixup (reads W columns) ----------------
__global__ __launch_bounds__(64)
void fixup_exact_wave(const float* __restrict__ X, const float* __restrict__ W,
                      float* __restrict__ O, const uint* __restrict__ flags,
                      uint cap, int K, int N)
{
    __shared__ float p[2048];

    uint count = flags[0];
    if (count > cap) count = cap;

    for (uint t = blockIdx.x; t < count; t += gridDim.x) {
        const uint idx = flags[1 + t];
        const int n = (int)(idx % (uint)N);
        const float* xrow = X + (size_t)(idx / (uint)N) * K;
        const float* wcol = W + n;

        if (K <= 2048) {
            for (int k = threadIdx.x; k < K; k += 64)
                p[k] = xrow[k] * sgnf(wcol[(size_t)k * N]);
            __syncthreads();
            if (threadIdx.x == 0) {
                float sum = 0.f;
                int ls = 0;
                while (ls < K) {
                    const int ke = (ls + 384 < K) ? (ls + 384) : K;
                    float part = 0.f;
                    for (int k = ls; k < ke; ++k) part += p[k];
                    sum += part;
                    ls = ke;
                }
                O[idx] = sgnf(sum);
            }
            __syncthreads();
        } else if (threadIdx.x == 0) {
            float sum = 0.f;
            int ls = 0;
            while (ls < K) {
                const int ke = (ls + 384 < K) ? (ls + 384) : K;
                float part = 0.f;
                for (int k = ls; k < ke; ++k)
                    part = fmaf(xrow[k], sgnf(wcol[(size_t)k * N]), part);
                sum += part;
                ls = ke;
            }
            O[idx] = sgnf(sum);
        }
    }
}

extern "C" void kernel_launch(void* const* d_in, const int* in_sizes, int n_in,
                              void* d_out, int out_size, void* d_ws, size_t ws_size,
                              hipStream_t stream) {
    // order-robust input binding (x = larger buffer)
    const float* X;
    const float* W;
    long long wsize;
    if ((long long)in_sizes[0] >= (long long)in_sizes[1]) {
        X = (const float*)d_in[0];
        W = (const float*)d_in[1]; wsize = in_sizes[1];
    } else {
        X = (const float*)d_in[1];
        W = (const float*)d_in[0]; wsize = in_sizes[0];
    }
    float* O = (float*)d_out;

    int K = 1;
    while ((long long)K * K < wsize) ++K;        // K = 2048
    const int N = K;
    const int M = (int)((long long)out_size / N);

    const size_t A2_BYTES = (size_t)M * 2 * K * 2;   // 64 MB
    const size_t BT_BYTES = (size_t)N * K * 2;       // 8 MB
    const size_t FLAG_OFF = A2_BYTES + BT_BYTES;
    const bool big_ws = (ws_size >= FLAG_OFF + (1u << 16)) &&
                        (M % 256 == 0) && (N % 256 == 0) &&
                        (K % 64 == 0) && (K >= 256) && (K <= 2048);

    if (big_ws) {
        ushort* A2 = (ushort*)d_ws;
        ushort* BT = (ushort*)((char*)d_ws + A2_BYTES);
        uint* flags = (uint*)((char*)d_ws + FLAG_OFF);
        unsigned long long c = (unsigned long long)((ws_size - FLAG_OFF) / 4) - 1ull;
        const uint cap = (uint)((c > 0x00FFFFFFull) ? 0x00FFFFFFull : c);

        const int pre_grid = M + (N / 64) * (K / 64);
        pre_pass<<<pre_grid, 256, 0, stream>>>(X, W, A2, BT, flags, M, K, N);
        const int nwg = (N / 256) * (M / 256);       // 256, % 8 == 0
        bulk_mfma_3c<<<nwg, 512, 0, stream>>>(A2, BT, O, flags, cap, M, N, K);
        fixup_exact_bt<<<2048, 64, 0, stream>>>(X, BT, O, flags, cap, K, N);
    } else {
        uint* flags = (uint*)d_ws;
        uint cap = 0;
        if (ws_size >= 8) {
            unsigned long long c = (unsigned long long)(ws_size / 4) - 1ull;
            cap = (uint)((c > 0x00FFFFFFull) ? 0x00FFFFFFull : c);
        }
        hipMemsetAsync(d_ws, 0, 4, stream);
        dim3 grid(N / 128, M / 128);
        bulk_mfma_fb<<<grid, 256, 0, stream>>>(X, W, O, flags, cap, M, N, K);
        fixup_exact_wave<<<2048, 64, 0, stream>>>(X, W, O, flags, cap, K, N);
    }
}